// Round 6
// baseline (229.577 us; speedup 1.0000x reference)
//
#include <hip/hip_runtime.h>
#include <hip/hip_fp16.h>

// GAT layer (2 heads, N=100k, D=64, E=1.7M), fp32. 4 kernels:
//   k_front   : per-node scores + bf16 cast of x  ||  per-tile bucket hist
//   k_col_scan: per-bucket exclusive prefix over tiles -> tbase, totals -> bcnt
//   k_binning : deterministic LDS counting-sort of tiles into bucket runs
//               (computes bbase from bcnt internally; block 0 publishes)
//   k_bucket_gather: one block per 256-row bucket; in-LDS row sort + e-values
//               + rowsums + coef, then per-row half-wave x-gather. No scol.
// out[i,:] = sum_e coef[e]*x[col[e],:], coef = 0.5*(e0/rs0 + e1/rs1).
// bf16 x-gather + half2 e-storage: added err ~ max|x|*2^-9 + 5e-4 << 0.037.
// NOTE: xh MUST be 128B-aligned (R4 lesson: misalignment = 1.8x FETCH).

#define D 64
#define ALPHA 0.2f
#define BSHIFT 8        // rows per bucket = 256
#define BROWS 256
#define MAXBUK 512      // supports N <= 131072
#define TILE 2048       // edges per binning tile
#define PK2 17          // pack = (row & 255) << 17 | col  (col < 2^17)
#define M17 ((1u << PK2) - 1u)
#define CAPE 8192       // LDS edge capacity per bucket (mean ~4450)

__device__ __forceinline__ unsigned bf16rne(float f) {
    unsigned u = __float_as_uint(f);
    u += 0x7fffu + ((u >> 16) & 1u);
    return u >> 16;
}
__device__ __forceinline__ unsigned packe(float e0, float e1) {
    __half2 h = __floats2half2_rn(e0, e1);
    return *reinterpret_cast<unsigned*>(&h);
}
__device__ __forceinline__ float2 unpacke(unsigned u) {
    __half2 h = *reinterpret_cast<__half2*>(&u);
    return __half22float2(h);
}
__device__ __forceinline__ float lrexp(float sc) {
    return __expf(sc > 0.f ? sc : ALPHA * sc);
}

// blocks [0, nblkA): per-node scores (1 wave/node) + bf16 cast.
// blocks [nblkA, nblkA+NT): per-tile bucket histogram -> tcnt (u16).
__global__ __launch_bounds__(256) void k_front(
    const float* __restrict__ x, const float* __restrict__ W,
    const float* __restrict__ a, float4* __restrict__ s,
    unsigned short* __restrict__ xh, const int* __restrict__ row,
    unsigned short* __restrict__ tcnt, int N, int E, int nblkA, int nbuk)
{
    __shared__ int h[MAXBUK];
    if ((int)blockIdx.x < nblkA) {
        int wid  = (blockIdx.x * 256 + threadIdx.x) >> 6;
        int lane = threadIdx.x & 63;
        if (wid >= N) return;
        float v = x[(size_t)wid * D + lane];
        xh[(size_t)wid * D + lane] = (unsigned short)bf16rne(v);
        float h0 = v * W[lane];
        float h1 = v * W[D + lane];
        float t0 = h0 * a[lane];          // src head0
        float t1 = h0 * a[D + lane];      // dst head0
        float t2 = h1 * a[2 * D + lane];  // src head1
        float t3 = h1 * a[3 * D + lane];  // dst head1
#pragma unroll
        for (int off = 32; off; off >>= 1) {
            t0 += __shfl_xor(t0, off);
            t1 += __shfl_xor(t1, off);
            t2 += __shfl_xor(t2, off);
            t3 += __shfl_xor(t3, off);
        }
        if (lane == 0) s[wid] = make_float4(t0, t1, t2, t3);
    } else {
        int tile = blockIdx.x - nblkA;
        int t = threadIdx.x, base = tile * TILE;
        int cnt = E - base; if (cnt > TILE) cnt = TILE;
        h[t] = 0; h[t + 256] = 0;
        __syncthreads();
        for (int i = t; i < cnt; i += 256) atomicAdd(&h[row[base + i] >> BSHIFT], 1);
        __syncthreads();
        tcnt[(size_t)tile * MAXBUK + t]       = (unsigned short)h[t];
        tcnt[(size_t)tile * MAXBUK + t + 256] = (unsigned short)h[t + 256];
    }
}

// MAXBUK blocks; block b: exclusive prefix of tcnt[:,b] over tiles (NT<=1024)
__global__ __launch_bounds__(256) void k_col_scan(
    const unsigned short* __restrict__ tcnt, int* __restrict__ tbase,
    int* __restrict__ bcnt, int NT, int nbuk)
{
    int b = blockIdx.x, t = threadIdx.x;
    if (b >= nbuk) { if (t == 0) bcnt[b] = 0; return; }
    __shared__ int wsum[256];
    int t4 = t * 4;
    int v0 = (t4     < NT) ? tcnt[(size_t)(t4    ) * MAXBUK + b] : 0;
    int v1 = (t4 + 1 < NT) ? tcnt[(size_t)(t4 + 1) * MAXBUK + b] : 0;
    int v2 = (t4 + 2 < NT) ? tcnt[(size_t)(t4 + 2) * MAXBUK + b] : 0;
    int v3 = (t4 + 3 < NT) ? tcnt[(size_t)(t4 + 3) * MAXBUK + b] : 0;
    int sv = v0 + v1 + v2 + v3;
    wsum[t] = sv;
    __syncthreads();
    for (int off = 1; off < 256; off <<= 1) {
        int add = (t >= off) ? wsum[t - off] : 0;
        __syncthreads();
        wsum[t] += add;
        __syncthreads();
    }
    int run = wsum[t] - sv;
    if (t4     < NT) { tbase[(size_t)(t4    ) * MAXBUK + b] = run; run += v0; }
    if (t4 + 1 < NT) { tbase[(size_t)(t4 + 1) * MAXBUK + b] = run; run += v1; }
    if (t4 + 2 < NT) { tbase[(size_t)(t4 + 2) * MAXBUK + b] = run; run += v2; }
    if (t4 + 3 < NT) { tbase[(size_t)(t4 + 3) * MAXBUK + b] = run; run += v3; }
    if (t == 255) bcnt[b] = wsum[255];
}

// deterministic tile binning; computes bbase (scan of bcnt) in-block
__global__ __launch_bounds__(256) void k_binning(
    const int* __restrict__ row, const int* __restrict__ col,
    const int* __restrict__ bcnt, const int* __restrict__ tbase,
    unsigned* __restrict__ ebuf, int* __restrict__ bbase_g, int E, int nbuk)
{
    __shared__ int lrow[TILE];
    __shared__ int lcol[TILE];
    __shared__ int h[MAXBUK];    // per-bucket count in this tile
    __shared__ int st[MAXBUK];   // local exclusive start
    __shared__ int gb[MAXBUK];   // deterministic global base
    __shared__ int cur[MAXBUK];  // local placement cursor
    __shared__ int w2[256];      // scan temp
    int t = threadIdx.x;
    int base = blockIdx.x * TILE;
    int cnt = E - base; if (cnt > TILE) cnt = TILE;

    h[t] = 0; h[t + 256] = 0;
    __syncthreads();

    int r[8], c[8], b[8];
#pragma unroll
    for (int j = 0; j < 8; j++) {
        int li = j * 256 + t;
        if (li < cnt) {
            int idx = base + li;
            r[j] = row[idx]; c[j] = col[idx]; b[j] = r[j] >> BSHIFT;
            atomicAdd(&h[b[j]], 1);
        } else b[j] = -1;
    }
    __syncthreads();

    // scan A: this tile's bucket histogram (2 entries/thread)
    int a0 = h[2 * t], a1 = h[2 * t + 1];
    int sv = a0 + a1;
    w2[t] = sv;
    __syncthreads();
    for (int off = 1; off < 256; off <<= 1) {
        int add = (t >= off) ? w2[t - off] : 0;
        __syncthreads();
        w2[t] += add;
        __syncthreads();
    }
    int run = w2[t] - sv;
    st[2 * t] = run;        st[2 * t + 1] = run + a0;
    cur[2 * t] = run;       cur[2 * t + 1] = run + a0;
    __syncthreads();   // before reusing w2

    // scan B: global bucket bases from bcnt (zeroed for b >= nbuk)
    int b0 = bcnt[2 * t], b1 = bcnt[2 * t + 1];
    int sb = b0 + b1;
    w2[t] = sb;
    __syncthreads();
    for (int off = 1; off < 256; off <<= 1) {
        int add = (t >= off) ? w2[t - off] : 0;
        __syncthreads();
        w2[t] += add;
        __syncthreads();
    }
    int runb = w2[t] - sb;
    gb[2 * t]     = runb      + tbase[(size_t)blockIdx.x * MAXBUK + 2 * t];
    gb[2 * t + 1] = runb + b0 + tbase[(size_t)blockIdx.x * MAXBUK + 2 * t + 1];
    if (blockIdx.x == 0) {
        bbase_g[2 * t] = runb; bbase_g[2 * t + 1] = runb + b0;
        if (t == 255) bbase_g[512] = runb + b0 + b1;
    }
    __syncthreads();

#pragma unroll
    for (int j = 0; j < 8; j++) {
        if (b[j] >= 0) {
            int p = atomicAdd(&cur[b[j]], 1);
            lrow[p] = r[j]; lcol[p] = c[j];
        }
    }
    __syncthreads();

    for (int i = t; i < cnt; i += 256) {
        int rr = lrow[i];
        int bb = rr >> BSHIFT;
        ebuf[gb[bb] + (i - st[bb])] =
            ((unsigned)(rr & (BROWS - 1)) << PK2) | (unsigned)lcol[i];
    }
}

// one block per 256-row bucket, 512 threads (8 waves):
//   A: row hist -> scan -> scatter (pk, half2(e0,e1)) into LDS; rowsum atomics
//   B: inv per row; B2: ev -> coef in place
//   C: per-row half-wave x-gather (2 edges per 256B load), coalesced out write
__global__ __launch_bounds__(512) void k_bucket_gather(
    const unsigned* __restrict__ xh2, const float4* __restrict__ s,
    const unsigned* __restrict__ ebuf, const int* __restrict__ bbase,
    float* __restrict__ out, int N)
{
    __shared__ unsigned pkA[CAPE];
    __shared__ unsigned evA[CAPE];   // half2(e0,e1), then f32 coef in place
    __shared__ int   hist[BROWS];
    __shared__ int   offs[BROWS + 1];
    __shared__ int   cursor[BROWS];
    __shared__ float rs0[BROWS], rs1[BROWS];
    __shared__ float rsx[BROWS], rsz[BROWS];
    __shared__ int   wsum[256];
    int b = blockIdx.x, t = threadIdx.x;
    int lo = b << BSHIFT;
    int s0 = bbase[b], s1 = bbase[b + 1];
    int seg = s1 - s0;

    if (t < BROWS) {
        int g = lo + t;
        float4 f = (g < N) ? s[g] : make_float4(0.f, 0.f, 0.f, 0.f);
        rsx[t] = f.x; rsz[t] = f.z;
        hist[t] = 0; rs0[t] = 0.f; rs1[t] = 0.f;
    }
    __syncthreads();

    if (seg <= CAPE) {   // fast path (always, for this input)
        for (int i = s0 + t; i < s1; i += 512)
            atomicAdd(&hist[ebuf[i] >> PK2], 1);
        __syncthreads();
        int a = 0;
        if (t < BROWS) { a = hist[t]; wsum[t] = a; }
        __syncthreads();
        for (int off = 1; off < 256; off <<= 1) {
            int add = 0;
            if (t < BROWS && t >= off) add = wsum[t - off];
            __syncthreads();
            if (t < BROWS) wsum[t] += add;
            __syncthreads();
        }
        if (t < BROWS) {
            offs[t] = wsum[t] - a; cursor[t] = wsum[t] - a;
            if (t == BROWS - 1) offs[BROWS] = wsum[t];
        }
        __syncthreads();
        for (int i = s0 + t; i < s1; i += 512) {
            unsigned pk = ebuf[i];
            int r = pk >> PK2, c = (int)(pk & M17);
            float4 sc = s[c];
            float e0 = lrexp(rsx[r] + sc.y);
            float e1 = lrexp(rsz[r] + sc.w);
            atomicAdd(&rs0[r], e0);
            atomicAdd(&rs1[r], e1);
            int p = atomicAdd(&cursor[r], 1);
            pkA[p] = pk; evA[p] = packe(e0, e1);
        }
        __syncthreads();
        if (t < BROWS) { rs0[t] = 0.5f / rs0[t]; rs1[t] = 0.5f / rs1[t]; }
        __syncthreads();
        for (int i = t; i < seg; i += 512) {
            unsigned pk = pkA[i];
            int r = pk >> PK2;
            float2 ef = unpacke(evA[i]);
            evA[i] = __float_as_uint(rs0[r] * ef.x + rs1[r] * ef.y);
        }
        __syncthreads();

        int wv = t >> 6, lane = t & 63, half = lane >> 5, li = lane & 31;
        for (int j = 0; j < 32; j++) {
            int r = wv * 32 + j;
            int g = lo + r;
            if (g >= N) continue;
            int st2 = offs[r], en = offs[r + 1];
            float acc0 = 0.f, acc1 = 0.f;
            int kk = st2 + half;
            for (; kk + 2 < en; kk += 4) {   // 2 edges in flight per half
                unsigned pka = pkA[kk],   pkb = pkA[kk + 2];
                float ca = __uint_as_float(evA[kk]);
                float cb = __uint_as_float(evA[kk + 2]);
                unsigned ua = xh2[(((unsigned)(pka & M17)) << 5) + li];
                unsigned ub = xh2[(((unsigned)(pkb & M17)) << 5) + li];
                acc0 += ca * __uint_as_float(ua << 16);
                acc1 += ca * __uint_as_float(ua & 0xffff0000u);
                acc0 += cb * __uint_as_float(ub << 16);
                acc1 += cb * __uint_as_float(ub & 0xffff0000u);
            }
            for (; kk < en; kk += 2) {
                unsigned pk = pkA[kk];
                float cf = __uint_as_float(evA[kk]);
                unsigned u = xh2[(((unsigned)(pk & M17)) << 5) + li];
                acc0 += cf * __uint_as_float(u << 16);
                acc1 += cf * __uint_as_float(u & 0xffff0000u);
            }
            acc0 += __shfl_xor(acc0, 32);
            acc1 += __shfl_xor(acc1, 32);
            if (half == 0)
                ((float2*)(out + (size_t)g * D))[li] = make_float2(acc0, acc1);
        }
    } else {   // chunked fallback (correctness insurance; not taken for this input)
        for (int i = s0 + t; i < s1; i += 512) {
            unsigned pk = ebuf[i];
            int r = pk >> PK2, c = (int)(pk & M17);
            float4 sc = s[c];
            atomicAdd(&rs0[r], lrexp(rsx[r] + sc.y));
            atomicAdd(&rs1[r], lrexp(rsz[r] + sc.w));
        }
        __syncthreads();
        if (t < BROWS) { rs0[t] = 0.5f / rs0[t]; rs1[t] = 0.5f / rs1[t]; }
        for (int idx = t; idx < BROWS * D; idx += 512) {
            int g = lo + (idx >> 6);
            if (g < N) out[(size_t)g * D + (idx & 63)] = 0.f;
        }
        __syncthreads();
        for (int base = s0; base < s1; base += CAPE) {
            int ce = base + CAPE; if (ce > s1) ce = s1;
            if (t < BROWS) hist[t] = 0;
            __syncthreads();
            for (int i = base + t; i < ce; i += 512)
                atomicAdd(&hist[ebuf[i] >> PK2], 1);
            __syncthreads();
            int a = 0;
            if (t < BROWS) { a = hist[t]; wsum[t] = a; }
            __syncthreads();
            for (int off = 1; off < 256; off <<= 1) {
                int add = 0;
                if (t < BROWS && t >= off) add = wsum[t - off];
                __syncthreads();
                if (t < BROWS) wsum[t] += add;
                __syncthreads();
            }
            if (t < BROWS) {
                offs[t] = wsum[t] - a; cursor[t] = wsum[t] - a;
                if (t == BROWS - 1) offs[BROWS] = wsum[t];
            }
            __syncthreads();
            for (int i = base + t; i < ce; i += 512) {
                unsigned pk = ebuf[i];
                int r = pk >> PK2, c = (int)(pk & M17);
                float4 sc = s[c];
                float coef = rs0[r] * lrexp(rsx[r] + sc.y)
                           + rs1[r] * lrexp(rsz[r] + sc.w);
                int p = atomicAdd(&cursor[r], 1);
                pkA[p] = pk; evA[p] = __float_as_uint(coef);
            }
            __syncthreads();
            int wv = t >> 6, lane = t & 63, half = lane >> 5, li = lane & 31;
            for (int j = 0; j < 32; j++) {
                int r = wv * 32 + j;
                int g = lo + r;
                if (g >= N) continue;
                int st2 = offs[r], en = offs[r + 1];
                float acc0 = 0.f, acc1 = 0.f;
                for (int kk = st2 + half; kk < en; kk += 2) {
                    unsigned pk = pkA[kk];
                    float cf = __uint_as_float(evA[kk]);
                    unsigned u = xh2[(((unsigned)(pk & M17)) << 5) + li];
                    acc0 += cf * __uint_as_float(u << 16);
                    acc1 += cf * __uint_as_float(u & 0xffff0000u);
                }
                acc0 += __shfl_xor(acc0, 32);
                acc1 += __shfl_xor(acc1, 32);
                if (half == 0) {
                    float2* o = (float2*)(out + (size_t)g * D);
                    float2 old = o[li];
                    o[li] = make_float2(old.x + acc0, old.y + acc1);
                }
            }
            __syncthreads();
        }
    }
}

extern "C" void kernel_launch(void* const* d_in, const int* in_sizes, int n_in,
                              void* d_out, int out_size, void* d_ws, size_t ws_size,
                              hipStream_t stream)
{
    const float* x  = (const float*)d_in[0];
    const int*   ei = (const int*)d_in[1];
    const float* W  = (const float*)d_in[2];
    const float* a  = (const float*)d_in[3];
    float*       out = (float*)d_out;
    int N = in_sizes[0] / D;
    int E = in_sizes[1] / 2;
    const int* row = ei;
    const int* col = ei + E;

    int NBUK = (N + BROWS - 1) >> BSHIFT;   // 391 for N=100000 (<= MAXBUK)
    int NT   = (E + TILE - 1) / TILE;       // 831 for E=1.7M (<= 1024)

    // workspace: every array 256B-aligned (xh row alignment is critical)
    uintptr_t wp = (uintptr_t)d_ws;
    auto alloc = [&wp](size_t bytes) -> void* {
        wp = (wp + 255) & ~(uintptr_t)255;
        void* p = (void*)wp;
        wp += bytes;
        return p;
    };
    unsigned short* xh    = (unsigned short*)alloc((size_t)N * D * 2);
    float4*         s     = (float4*)alloc((size_t)N * sizeof(float4));
    unsigned*       ebuf  = (unsigned*)alloc((size_t)E * sizeof(unsigned));
    int*            tbase = (int*)alloc((size_t)NT * MAXBUK * sizeof(int));
    int*            bcnt  = (int*)alloc(MAXBUK * sizeof(int));
    int*            bbase = (int*)alloc((MAXBUK + 4) * sizeof(int));
    unsigned short* tcnt  = (unsigned short*)alloc((size_t)NT * MAXBUK * 2);

    int nblkA = (N + 3) / 4;
    k_front<<<nblkA + NT, 256, 0, stream>>>(x, W, a, s, xh, row, tcnt, N, E, nblkA, NBUK);
    k_col_scan<<<MAXBUK, 256, 0, stream>>>(tcnt, tbase, bcnt, NT, NBUK);
    k_binning<<<NT, 256, 0, stream>>>(row, col, bcnt, tbase, ebuf, bbase, E, NBUK);
    k_bucket_gather<<<NBUK, 512, 0, stream>>>((const unsigned*)xh, s, ebuf, bbase, out, N);
}

// Round 7
// 188.315 us; speedup vs baseline: 1.2191x; 1.2191x over previous
//
#include <hip/hip_runtime.h>

// GAT layer (2 heads, N=100k, D=64, E=1.7M), fp32. 6 kernels:
//   k_front      : per-node scores + bf16 cast of x || per-tile bucket hist
//   k_col_scan   : per-bucket exclusive prefix over tiles -> tbase, totals
//   k_bucket_scan: exclusive scan of bucket totals -> bbase
//   k_binning    : LDS counting-sort of tiles (hist REUSED from tcnt)
//   k_rowsort    : per-bucket row sort (1024 thr), XCD-local scatter
//   k_gather     : per-node wave gather, quarter-wave: 4 edges per iteration
// out[i,:] = sum_e coef[e]*x[col[e],:], coef = 0.5*(e0/rs0 + e1/rs1).
// bf16 x-gather: convex combination per head -> err <= max|x|*2^-9 << 0.037.
// LESSONS: (R4) xh must be 128B-aligned or FETCH x1.8. (R6) never trade
// occupancy for locality on the gather: 391-block fused version = 29% occ,
// 2x slower despite 30% less FETCH. Launch gap ~2us -> fusion is minor.

#define D 64
#define ALPHA 0.2f
#define CAP 96          // LDS stash per node in k_gather (multiple of 8)
#define BSHIFT 9        // rows per bucket = 512
#define BROWS 512
#define MAXBUK 256      // supports N <= 131072
#define TILE 2048       // edges per tile
#define PACKSHIFT 23    // pack = (row & 511) << 23 | col  (col < 2^23)
#define COLMASK ((1u << PACKSHIFT) - 1u)

__device__ __forceinline__ unsigned bf16rne(float f) {
    unsigned u = __float_as_uint(f);
    u += 0x7fffu + ((u >> 16) & 1u);
    return u >> 16;
}
__device__ __forceinline__ float lrexp(float sc) {
    return __expf(sc > 0.f ? sc : ALPHA * sc);
}

// blocks [0, nblkA): per-node scores (1 wave/node) + bf16 cast.
// blocks [nblkA, nblkA+NT): per-tile bucket histogram -> tcnt (u16).
__global__ __launch_bounds__(256) void k_front(
    const float* __restrict__ x, const float* __restrict__ W,
    const float* __restrict__ a, float4* __restrict__ s,
    unsigned short* __restrict__ xh, const int* __restrict__ row,
    unsigned short* __restrict__ tcnt, int N, int E, int nblkA)
{
    __shared__ int h[MAXBUK];
    if ((int)blockIdx.x < nblkA) {
        int wid  = (blockIdx.x * 256 + threadIdx.x) >> 6;
        int lane = threadIdx.x & 63;
        if (wid >= N) return;
        float v = x[(size_t)wid * D + lane];
        xh[(size_t)wid * D + lane] = (unsigned short)bf16rne(v);
        float h0 = v * W[lane];
        float h1 = v * W[D + lane];
        float t0 = h0 * a[lane];          // src head0
        float t1 = h0 * a[D + lane];      // dst head0
        float t2 = h1 * a[2 * D + lane];  // src head1
        float t3 = h1 * a[3 * D + lane];  // dst head1
#pragma unroll
        for (int off = 32; off; off >>= 1) {
            t0 += __shfl_xor(t0, off);
            t1 += __shfl_xor(t1, off);
            t2 += __shfl_xor(t2, off);
            t3 += __shfl_xor(t3, off);
        }
        if (lane == 0) s[wid] = make_float4(t0, t1, t2, t3);
    } else {
        int tile = blockIdx.x - nblkA;
        int t = threadIdx.x, base = tile * TILE;
        int cnt = E - base; if (cnt > TILE) cnt = TILE;
        h[t] = 0;
        __syncthreads();
        for (int i = t; i < cnt; i += 256) atomicAdd(&h[row[base + i] >> BSHIFT], 1);
        __syncthreads();
        tcnt[(size_t)tile * MAXBUK + t] = (unsigned short)h[t];
    }
}

// NBUK blocks; block b: exclusive prefix of tcnt[:,b] over tiles (NT <= 1024)
__global__ __launch_bounds__(256) void k_col_scan(
    const unsigned short* __restrict__ tcnt, int* __restrict__ tbase,
    int* __restrict__ bcnt, int NT)
{
    __shared__ int wsum[256];
    int b = blockIdx.x, t = threadIdx.x;
    int t4 = t * 4;
    int v0 = (t4     < NT) ? tcnt[(size_t)(t4    ) * MAXBUK + b] : 0;
    int v1 = (t4 + 1 < NT) ? tcnt[(size_t)(t4 + 1) * MAXBUK + b] : 0;
    int v2 = (t4 + 2 < NT) ? tcnt[(size_t)(t4 + 2) * MAXBUK + b] : 0;
    int v3 = (t4 + 3 < NT) ? tcnt[(size_t)(t4 + 3) * MAXBUK + b] : 0;
    int sv = v0 + v1 + v2 + v3;
    wsum[t] = sv;
    __syncthreads();
    for (int off = 1; off < 256; off <<= 1) {
        int add = (t >= off) ? wsum[t - off] : 0;
        __syncthreads();
        wsum[t] += add;
        __syncthreads();
    }
    int run = wsum[t] - sv;
    if (t4     < NT) { tbase[(size_t)(t4    ) * MAXBUK + b] = run; run += v0; }
    if (t4 + 1 < NT) { tbase[(size_t)(t4 + 1) * MAXBUK + b] = run; run += v1; }
    if (t4 + 2 < NT) { tbase[(size_t)(t4 + 2) * MAXBUK + b] = run; run += v2; }
    if (t4 + 3 < NT) { tbase[(size_t)(t4 + 3) * MAXBUK + b] = run; run += v3; }
    if (t == 255) bcnt[b] = wsum[255];
}

// single-block exclusive scan of bucket totals -> bbase (+ total at [nbuk])
__global__ void k_bucket_scan(const int* __restrict__ bcnt,
                              int* __restrict__ bbase, int nbuk)
{
    __shared__ int sd[MAXBUK];
    int t = threadIdx.x;
    int v = (t < nbuk) ? bcnt[t] : 0;
    sd[t] = v;
    __syncthreads();
    for (int off = 1; off < MAXBUK; off <<= 1) {
        int add = (t >= off) ? sd[t - off] : 0;
        __syncthreads();
        sd[t] += add;
        __syncthreads();
    }
    if (t < nbuk) bbase[t] = sd[t] - v;
    if (t == nbuk - 1) bbase[nbuk] = sd[t];
}

// deterministic tile binning; per-tile hist comes from tcnt (no recompute)
__global__ __launch_bounds__(256) void k_binning(
    const int* __restrict__ row, const int* __restrict__ col,
    const unsigned short* __restrict__ tcnt, const int* __restrict__ bbase,
    const int* __restrict__ tbase, unsigned* __restrict__ ebuf, int E)
{
    __shared__ int lrow[TILE];
    __shared__ int lcol[TILE];
    __shared__ int st[MAXBUK];   // local exclusive start
    __shared__ int gb[MAXBUK];   // deterministic global base
    __shared__ int cur[MAXBUK];  // local placement cursor
    __shared__ int wsum[256];
    int t = threadIdx.x;
    int tile = blockIdx.x;
    int base = tile * TILE;
    int cnt = E - base; if (cnt > TILE) cnt = TILE;

    int h = tcnt[(size_t)tile * MAXBUK + t];
    wsum[t] = h;
    __syncthreads();
    for (int off = 1; off < 256; off <<= 1) {
        int add = (t >= off) ? wsum[t - off] : 0;
        __syncthreads();
        wsum[t] += add;
        __syncthreads();
    }
    int start = wsum[t] - h;
    st[t]  = start;
    cur[t] = start;
    gb[t]  = bbase[t] + tbase[(size_t)tile * MAXBUK + t];
    __syncthreads();

    for (int i = t; i < cnt; i += 256) {
        int r = row[base + i], c = col[base + i];
        int p = atomicAdd(&cur[r >> BSHIFT], 1);
        lrow[p] = r; lcol[p] = c;
    }
    __syncthreads();

    for (int i = t; i < cnt; i += 256) {
        int rr = lrow[i];
        int bb = rr >> BSHIFT;
        ebuf[gb[bb] + (i - st[bb])] =
            ((unsigned)(rr & (BROWS - 1)) << PACKSHIFT) | (unsigned)lcol[i];
    }
}

// one block per bucket (1024 thr = 16 waves): row sort, L2-local scatter
__global__ __launch_bounds__(1024) void k_rowsort(
    const unsigned* __restrict__ ebuf, const int* __restrict__ bbase,
    int* __restrict__ offsets, int* __restrict__ counts,
    int* __restrict__ scol, int N)
{
    __shared__ int hist[BROWS];
    __shared__ int offs[BROWS];
    __shared__ int wsum[256];
    int b = blockIdx.x, t = threadIdx.x;
    int lo = b << BSHIFT;
    int s0 = bbase[b], s1 = bbase[b + 1];

    if (t < BROWS) hist[t] = 0;
    __syncthreads();
    for (int i = s0 + t; i < s1; i += 1024)
        atomicAdd(&hist[ebuf[i] >> PACKSHIFT], 1);
    __syncthreads();

    int a0 = 0, a1 = 0, sv = 0;
    if (t < 256) { a0 = hist[2 * t]; a1 = hist[2 * t + 1]; sv = a0 + a1; wsum[t] = sv; }
    __syncthreads();
    for (int off = 1; off < 256; off <<= 1) {
        int add = 0;
        if (t < 256 && t >= off) add = wsum[t - off];
        __syncthreads();
        if (t < 256) wsum[t] += add;
        __syncthreads();
    }
    if (t < 256) { int run = wsum[t] - sv; offs[2 * t] = run; offs[2 * t + 1] = run + a0; }
    __syncthreads();

    if (t < BROWS) {
        int rg = lo + t;
        if (rg < N) { offsets[rg] = s0 + offs[t]; counts[rg] = hist[t]; }
    }
    __syncthreads();
    if (t < BROWS) hist[t] = offs[t];   // hist -> cursor
    __syncthreads();

    for (int i = s0 + t; i < s1; i += 1024) {
        unsigned pk = ebuf[i];
        int p = atomicAdd(&hist[pk >> PACKSHIFT], 1);
        scol[s0 + p] = (int)(pk & COLMASK);
    }
}

// 4 nodes/block, 1 wave/node. Phase 1: lane-parallel e-values + rowsums,
// stash (col<<5, e0, e1). Phase 1.5: coef into lpair.y. Phase 2: four
// 16-lane quarters, one edge each per iter, uint2 (=4 bf16 feats) per lane
// -> 4 edges per 128B-coalesced load instruction. No barriers (wave-private).
__global__ __launch_bounds__(256) void k_gather(
    const unsigned* __restrict__ xh2, const float4* __restrict__ s,
    const int* __restrict__ offsets, const int* __restrict__ counts,
    const int* __restrict__ scol, float* __restrict__ out, int N)
{
    __shared__ float  le0[4][CAP];
    __shared__ float  le1[4][CAP];
    __shared__ float2 lpair[4][CAP];   // .x = bitcast (col<<5), .y = coef
    int w    = threadIdx.x >> 6;
    int lane = threadIdx.x & 63;
    int n    = blockIdx.x * 4 + w;
    bool valid = (n < N);
    int start = 0, cnt = 0;
    float4 srow = make_float4(0.f, 0.f, 0.f, 0.f);
    if (valid) { start = offsets[n]; cnt = counts[n]; srow = s[n]; }

    float sum0 = 0.f, sum1 = 0.f;
    for (int k = lane; k < cnt; k += 64) {
        int c = scol[start + k];
        float4 sc = s[c];
        float e0 = lrexp(srow.x + sc.y);
        float e1 = lrexp(srow.z + sc.w);
        sum0 += e0; sum1 += e1;
        if (k < CAP) { lpair[w][k].x = __int_as_float(c << 5); le0[w][k] = e0; le1[w][k] = e1; }
    }
    int m  = cnt < CAP ? cnt : CAP;
    int mp = (m + 7) & ~7;          // zero-pad stash to multiple of 8
    {
        int k = m + lane;
        if (k < mp) { lpair[w][k].x = __int_as_float(0); le0[w][k] = 0.f; le1[w][k] = 0.f; }
    }
#pragma unroll
    for (int off = 32; off; off >>= 1) {
        sum0 += __shfl_xor(sum0, off);
        sum1 += __shfl_xor(sum1, off);
    }
    if (!valid) return;
    float inv0 = 0.5f / sum0, inv1 = 0.5f / sum1;
    for (int k = lane; k < mp; k += 64)     // phase 1.5: precombined coef
        lpair[w][k].y = inv0 * le0[w][k] + inv1 * le1[w][k];
    // stash arrays are wave-private ([w] slice) -> no barrier needed

    int q  = lane >> 4;      // quarter 0..3: edge parity mod 4
    int li = lane & 15;      // feature-quad index (features 4li..4li+3)
    float a0 = 0.f, a1 = 0.f, a2 = 0.f, a3 = 0.f;
    for (int k = 0; k < mp; k += 8) {
#pragma unroll
        for (int j = 0; j < 2; j++) {
            int kk = k + 4 * j + q;
            float2 pr = lpair[w][kk];
            unsigned cb = (unsigned)__float_as_int(pr.x);
            uint2 u = *(const uint2*)(xh2 + cb + 2 * li);
            float cf = pr.y;
            a0 += cf * __uint_as_float(u.x << 16);
            a1 += cf * __uint_as_float(u.x & 0xffff0000u);
            a2 += cf * __uint_as_float(u.y << 16);
            a3 += cf * __uint_as_float(u.y & 0xffff0000u);
        }
    }
    for (int kk = CAP + q; kk < cnt; kk += 4) {  // overflow (degree > CAP)
        int c = scol[start + kk];
        float4 sc = s[c];
        float cf = inv0 * lrexp(srow.x + sc.y) + inv1 * lrexp(srow.z + sc.w);
        uint2 u = *(const uint2*)(xh2 + ((unsigned)c << 5) + 2 * li);
        a0 += cf * __uint_as_float(u.x << 16);
        a1 += cf * __uint_as_float(u.x & 0xffff0000u);
        a2 += cf * __uint_as_float(u.y << 16);
        a3 += cf * __uint_as_float(u.y & 0xffff0000u);
    }
    // reduce across quarters (same li in every quarter)
    a0 += __shfl_xor(a0, 16); a0 += __shfl_xor(a0, 32);
    a1 += __shfl_xor(a1, 16); a1 += __shfl_xor(a1, 32);
    a2 += __shfl_xor(a2, 16); a2 += __shfl_xor(a2, 32);
    a3 += __shfl_xor(a3, 16); a3 += __shfl_xor(a3, 32);
    if (q == 0)
        ((float4*)(out + (size_t)n * D))[li] = make_float4(a0, a1, a2, a3);
}

extern "C" void kernel_launch(void* const* d_in, const int* in_sizes, int n_in,
                              void* d_out, int out_size, void* d_ws, size_t ws_size,
                              hipStream_t stream)
{
    const float* x  = (const float*)d_in[0];
    const int*   ei = (const int*)d_in[1];
    const float* W  = (const float*)d_in[2];
    const float* a  = (const float*)d_in[3];
    float*       out = (float*)d_out;
    int N = in_sizes[0] / D;
    int E = in_sizes[1] / 2;
    const int* row = ei;
    const int* col = ei + E;

    int NBUK = (N + BROWS - 1) >> BSHIFT;   // 196 for N=100000 (<= MAXBUK)
    int NT   = (E + TILE - 1) / TILE;       // 831 for E=1.7M (<= 1024)

    // workspace: every array 256B-aligned (xh row alignment is critical)
    uintptr_t wp = (uintptr_t)d_ws;
    auto alloc = [&wp](size_t bytes) -> void* {
        wp = (wp + 255) & ~(uintptr_t)255;
        void* p = (void*)wp;
        wp += bytes;
        return p;
    };
    unsigned short* xh      = (unsigned short*)alloc((size_t)N * D * 2);
    float4*         s       = (float4*)alloc((size_t)N * sizeof(float4));
    int*            offsets = (int*)alloc((size_t)N * sizeof(int));
    int*            counts  = (int*)alloc((size_t)N * sizeof(int));
    int*            scol    = (int*)alloc((size_t)E * sizeof(int));
    unsigned*       ebuf    = (unsigned*)alloc((size_t)E * sizeof(unsigned));
    int*            tbase   = (int*)alloc((size_t)NT * MAXBUK * sizeof(int));
    int*            bcnt    = (int*)alloc(MAXBUK * sizeof(int));
    int*            bbase   = (int*)alloc((MAXBUK + 4) * sizeof(int));
    unsigned short* tcnt    = (unsigned short*)alloc((size_t)NT * MAXBUK * 2);

    int nblkA = (N + 3) / 4;
    k_front<<<nblkA + NT, 256, 0, stream>>>(x, W, a, s, xh, row, tcnt, N, E, nblkA);
    k_col_scan<<<NBUK, 256, 0, stream>>>(tcnt, tbase, bcnt, NT);
    k_bucket_scan<<<1, MAXBUK, 0, stream>>>(bcnt, bbase, NBUK);
    k_binning<<<NT, 256, 0, stream>>>(row, col, tcnt, bbase, tbase, ebuf, E);
    k_rowsort<<<NBUK, 1024, 0, stream>>>(ebuf, bbase, offsets, counts, scol, N);
    k_gather<<<(N + 3) / 4, 256, 0, stream>>>((const unsigned*)xh, s, offsets, counts, scol, out, N);
}